// Round 9
// baseline (547.772 us; speedup 1.0000x reference)
//
#include <hip/hip_runtime.h>
#include <cmath>

// ---------------------------------------------------------------------------
// NeuralMemory R9: fp16 pipeline; B-operand direct-from-global (L1/L2) for
// weight GEMMs (halves the LDS-pipe load); merged 4-segment GRADW dispatch;
// fp16 activations everywhere between kernels (fp32 only for dh accum + out).
// ---------------------------------------------------------------------------

namespace {

constexpr int Bb   = 2;
constexpr int Ss   = 2048;
constexpr int Dd   = 512;
constexpr int Mm   = 64;
constexpr int NCc  = 16;
constexpr int NHh  = 8;
constexpr int HD   = 64;
constexpr int WINw = 256;
constexpr int Nn   = Mm + Ss;    // 2112
constexpr int Rr   = Bb * Nn;    // 4224
constexpr int NBD  = Rr * Dd;
constexpr float MAXLR = 0.1f;
constexpr float GS   = 256.0f;   // gradient-stream scale (fp16 subnormal guard)
constexpr int WEL  = 262144;

typedef __attribute__((ext_vector_type(8))) short short8;
typedef __attribute__((ext_vector_type(8))) _Float16 half8;
typedef __attribute__((ext_vector_type(4))) float f32x4;

__device__ __forceinline__ float sigf(float x)  { return 1.0f / (1.0f + __expf(-x)); }
__device__ __forceinline__ float siluf(float x) { return x * sigf(x); }
__device__ __forceinline__ float dsiluf(float x){ float s = sigf(x); return s * (1.0f + x * (1.0f - s)); }
__device__ __forceinline__ unsigned short f2h(float f) {
    _Float16 h = (_Float16)f;
    return *(unsigned short*)&h;
}
__device__ __forceinline__ float h2f(unsigned short u) {
    return (float)(*(_Float16*)&u);
}
__device__ __forceinline__ int swz(int u) { return u ^ ((u >> 4) & 7); }

// ---- build xm (fp16) ------------------------------------------------------
__global__ void k_build_xm(const float* __restrict__ x, const float* __restrict__ meta,
                           unsigned short* __restrict__ xh) {
    int i = blockIdx.x * 256 + threadIdx.x;      // float4 units
    if (i >= Rr * 128) return;
    int c = i & 127, r = i >> 7;
    int b = r / Nn, t = r - b * Nn;
    float4 v = (t < Mm) ? ((const float4*)meta)[t * 128 + c]
                        : ((const float4*)x)[(size_t)(b * Ss + (t - Mm)) * 128 + c];
    float vv[4] = { v.x, v.y, v.z, v.w };
    unsigned short h[4];
    #pragma unroll
    for (int e = 0; e < 4; ++e) h[e] = f2h(vv[e]);
    *(ushort4*)(xh + (size_t)i * 4) = *(ushort4*)h;
}

// ---- per-row scalar gates -------------------------------------------------
__global__ void k_gates(const unsigned short* __restrict__ xh,
                        const float* __restrict__ lw, const float* __restrict__ lb,
                        const float* __restrict__ fw, const float* __restrict__ fb,
                        const float* __restrict__ mw, const float* __restrict__ mb,
                        float* __restrict__ lr_t, float* __restrict__ fg_t, float* __restrict__ mo_t) {
    int r = blockIdx.x * 4 + (threadIdx.x >> 6);
    int lane = threadIdx.x & 63;
    if (r >= Rr) return;
    float s0 = 0.f, s1 = 0.f, s2 = 0.f;
    for (int j = lane; j < Dd; j += 64) {
        float v = h2f(xh[(size_t)r * Dd + j]);
        s0 += v * lw[j]; s1 += v * fw[j]; s2 += v * mw[j];
    }
    #pragma unroll
    for (int off = 32; off; off >>= 1) {
        s0 += __shfl_down(s0, off, 64);
        s1 += __shfl_down(s1, off, 64);
        s2 += __shfl_down(s2, off, 64);
    }
    if (lane == 0) {
        lr_t[r] = MAXLR * sigf(s0 + lb[0]);
        fg_t[r] = sigf(s1 + fb[0]);
        mo_t[r] = sigf(s2 + mb[0]);
    }
}

__global__ void k_gate_means(const float* __restrict__ lr_t, const float* __restrict__ fg_t,
                             const float* __restrict__ mo_t, float* __restrict__ scal) {
    __shared__ float red[256];
    const float* ptrs[3] = { fg_t, lr_t, mo_t };
    for (int w = 0; w < 3; ++w) {
        float acc = 0.f;
        for (int i = threadIdx.x; i < Rr; i += 256) acc += ptrs[w][i];
        red[threadIdx.x] = acc; __syncthreads();
        for (int off = 128; off; off >>= 1) {
            if (threadIdx.x < off) red[threadIdx.x] += red[threadIdx.x + off];
            __syncthreads();
        }
        if (threadIdx.x == 0) scal[w] = red[0] / (float)Rr;
        __syncthreads();
    }
}

// ---- weight convert via LDS transpose: W[r][c] fp32 -> WT[c][r] fp16 ------
struct WC { const float* w[11]; unsigned short* th[11]; unsigned short* nh[11]; };
__global__ __launch_bounds__(256) void k_wconv(WC wc) {
    __shared__ float T[64][65];
    int seg = blockIdx.z;
    int r0 = blockIdx.y * 64, c0 = blockIdx.x * 64;
    int tr = threadIdx.x >> 2, tc = (threadIdx.x & 3) * 16;
    const float* wsrc = wc.w[seg] + (size_t)(r0 + tr) * 512 + c0 + tc;
    float vals[16];
    #pragma unroll
    for (int q = 0; q < 4; ++q) *(float4*)&vals[q * 4] = *(const float4*)(wsrc + q * 4);
    #pragma unroll
    for (int e = 0; e < 16; ++e) T[tr][tc + e] = vals[e];
    if (wc.nh[seg]) {
        unsigned short nh16[16];
        #pragma unroll
        for (int e = 0; e < 16; ++e) nh16[e] = f2h(vals[e]);
        unsigned short* np = wc.nh[seg] + (size_t)(r0 + tr) * 512 + c0 + tc;
        *(short8*)np = *(short8*)nh16; *(short8*)(np + 8) = *(short8*)(nh16 + 8);
    }
    __syncthreads();
    int c = threadIdx.x >> 2, rb = (threadIdx.x & 3) * 16;
    unsigned short o16[16];
    #pragma unroll
    for (int e = 0; e < 16; ++e) o16[e] = f2h(T[rb + e][c]);
    unsigned short* tp = wc.th[seg] + (size_t)(c0 + c) * 512 + r0 + rb;
    *(short8*)tp = *(short8*)o16; *(short8*)(tp + 8) = *(short8*)(o16 + 8);
}

// ---- MFMA GEMM: 64x64 tile, BK=64, 256 thr, fp16 --------------------------
// TA=0: A row-major fp16 staged in LDS (swz). TA=1: A [k][m] staged (GRAD4).
// TB=0: B [n][k] weights read DIRECT from global (L1/L2-resident; no LDS).
// TB=1: B [k][n] staged in LDS (GRAD4 path).
// GRAD4: blockIdx.z = seg*11+kz over 4 (A,B) pairs; writes raw slabs to C.
// EPI: 0 fp32 C(+bias,+accum) | 1 silu->oh | 2 exA+silu->oh | 3 GS*dpred->oh
//      4 accum fp32 C + vv*dsilu(exD)->oh | 5 preact->oh2, silu->oh
//      6 preact->oh2, exA+silu->oh | 7 bias+slice fp32->C | 8 bias+fp16->oh
struct TriW { const unsigned short* bh; const float* bias; unsigned short* ch; };
struct TriSet { TriW t[3]; };
struct Grad4 { const unsigned short* a[4]; const unsigned short* b[4]; };

template<int TA, int TB, bool SPLITK, int EPI, bool MULTI, bool GRAD4>
__global__ __launch_bounds__(256) void k_mm(
        const unsigned short* Ap, const unsigned short* Bh_,
        float* C, const float* bias,
        const unsigned short* __restrict__ exA,
        const unsigned short* __restrict__ exD,
        const float* __restrict__ lrp,
        unsigned short* oh, unsigned short* oh2, TriSet ts, Grad4 g4,
        int Md, int Nd, int Kd, int accum) {
    __shared__ char smem[16384];
    unsigned short* AH = (unsigned short*)smem;   // 4096 halves
    unsigned short* BH = AH + 4096;               // only used when TB==1
    const int tid = threadIdx.x;
    const int m0 = blockIdx.x * 64, n0 = blockIdx.y * 64;
    if constexpr (MULTI) {
        const TriW& tw = ts.t[blockIdx.z];
        Bh_ = tw.bh; bias = tw.bias; oh = tw.ch;
    }
    int kbg = 0, ke = Kd;
    if constexpr (GRAD4) {
        int seg = blockIdx.z / 11, kz = blockIdx.z - seg * 11;
        kbg = kz * 384; ke = kbg + 384;
        C += (size_t)blockIdx.z * Md * Nd;
        Ap = g4.a[seg]; Bh_ = g4.b[seg];
    } else if constexpr (SPLITK) {
        int kc = Kd / gridDim.z;
        kbg = blockIdx.z * kc; ke = kbg + kc;
        C += (size_t)blockIdx.z * Md * Nd;
    }
    const int astr = (TA == 0) ? Kd : Md;

    f32x4 acc[2][2];
    #pragma unroll
    for (int i = 0; i < 2; ++i)
        #pragma unroll
        for (int j = 0; j < 2; ++j)
            #pragma unroll
            for (int v = 0; v < 4; ++v) acc[i][j][v] = 0.f;

    short8 pA0, pA1, pB0, pB1;

    const int wv = tid >> 6, lr16 = tid & 15, lq = (tid >> 4) & 3;
    const int wm = wv & 1, wn = wv >> 1;
    // B-direct per-lane base (TB==0)
    const unsigned short* bdir = nullptr;
    if constexpr (TB == 0)
        bdir = Bh_ + (size_t)(n0 + wn * 32 + lr16) * Kd + lq * 8;

    auto gload = [&](int k0) {
        if constexpr (TA == 0) {
            int r = tid >> 2, ks2 = (tid & 3) * 16;
            const unsigned short* ah = Ap + (size_t)(m0 + r) * astr + k0 + ks2;
            pA0 = *(const short8*)ah; pA1 = *(const short8*)(ah + 8);
        } else {
            int kr = tid >> 2, ms = (tid & 3) * 16;
            const unsigned short* ah = Ap + (size_t)(k0 + kr) * astr + m0 + ms;
            pA0 = *(const short8*)ah; pA1 = *(const short8*)(ah + 8);
        }
        if constexpr (TB == 1) {
            int kr = tid >> 2, nseg = (tid & 3) * 16;
            const unsigned short* bh = Bh_ + (size_t)(k0 + kr) * Nd + n0 + nseg;
            pB0 = *(const short8*)bh; pB1 = *(const short8*)(bh + 8);
        }
    };
    auto lstore = [&]() {
        if constexpr (TA == 0) {
            int r = tid >> 2, ks2 = (tid & 3) * 16;
            int f = r >> 4, rr = r & 15, kf = ks2 >> 5, q = (ks2 >> 3) & 3;
            int F = (f * 2 + kf) * 4 + q;
            int u0 = swz(F * 16 + rr) * 8, u1 = swz((F + 1) * 16 + rr) * 8;
            *(short8*)(AH + u0) = pA0; *(short8*)(AH + u1) = pA1;
        } else {
            int kr = tid >> 2, ms = (tid & 3) * 16;
            int f = ms >> 4, kf = kr >> 5, q = (kr >> 3) & 3, kk = kr & 7;
            int F = (f * 2 + kf) * 4 + q;
            unsigned short tmp[16];
            *(short8*)tmp = pA0; *(short8*)(tmp + 8) = pA1;
            #pragma unroll
            for (int e = 0; e < 16; ++e) AH[swz((F << 4) | e) * 8 + kk] = tmp[e];
        }
        if constexpr (TB == 1) {
            int kr = tid >> 2, nseg = (tid & 3) * 16;
            int f = nseg >> 4, kf = kr >> 5, q = (kr >> 3) & 3, kk = kr & 7;
            int F = (f * 2 + kf) * 4 + q;
            unsigned short tmp[16];
            *(short8*)tmp = pB0; *(short8*)(tmp + 8) = pB1;
            #pragma unroll
            for (int e = 0; e < 16; ++e) BH[swz((F << 4) | e) * 8 + kk] = tmp[e];
        }
    };

    gload(kbg); lstore();
    __syncthreads();
    for (int k0 = kbg; k0 < ke; k0 += 64) {
        bool more = (k0 + 64) < ke;
        if (more) gload(k0 + 64);
        half8 gb[2][2];
        if constexpr (TB == 0) {
            #pragma unroll
            for (int kf = 0; kf < 2; ++kf)
                #pragma unroll
                for (int j = 0; j < 2; ++j)
                    gb[kf][j] = *(const half8*)(bdir + (size_t)j * 16 * Kd + k0 + kf * 32);
        }
        #pragma unroll
        for (int kf = 0; kf < 2; ++kf) {
            half8 fa[2], fb[2];
            #pragma unroll
            for (int i = 0; i < 2; ++i) {
                int u = swz((((wm * 2 + i) * 2 + kf) * 4 + lq) * 16 + lr16);
                fa[i] = *(const half8*)(AH + u * 8);
            }
            #pragma unroll
            for (int j = 0; j < 2; ++j) {
                if constexpr (TB == 0) fb[j] = gb[kf][j];
                else {
                    int u = swz((((wn * 2 + j) * 2 + kf) * 4 + lq) * 16 + lr16);
                    fb[j] = *(const half8*)(BH + u * 8);
                }
            }
            #pragma unroll
            for (int i = 0; i < 2; ++i)
                #pragma unroll
                for (int j = 0; j < 2; ++j)
                    acc[i][j] = __builtin_amdgcn_mfma_f32_16x16x32_f16(fa[i], fb[j], acc[i][j], 0, 0, 0);
        }
        if (more) { __syncthreads(); lstore(); __syncthreads(); }
    }
    __syncthreads();

    // ---- epilogue: acc -> swizzled LDS fp32 -> row-major per-thread ----
    float* EP = (float*)smem;
    #pragma unroll
    for (int i = 0; i < 2; ++i)
        #pragma unroll
        for (int j = 0; j < 2; ++j)
            #pragma unroll
            for (int v = 0; v < 4; ++v) {
                int row = wm * 32 + i * 16 + lq * 4 + v;
                int col = wn * 32 + j * 16 + lr16;
                int u = col >> 2, up = u ^ (row & 15);
                EP[row * 64 + up * 4 + (col & 3)] = acc[i][j][v];
            }
    __syncthreads();
    int r = tid >> 2, cg = tid & 3;
    float vv[16];
    #pragma unroll
    for (int uu = 0; uu < 4; ++uu) {
        int u = cg * 4 + uu;
        *(float4*)&vv[uu * 4] = *(const float4*)&EP[r * 64 + ((u ^ (r & 15)) * 4)];
    }
    int m = m0 + r, nb = n0 + cg * 16;
    size_t idx = (size_t)m * Nd + nb;

    if constexpr (SPLITK || GRAD4) {
        #pragma unroll
        for (int uu = 0; uu < 4; ++uu) *(float4*)(C + idx + uu * 4) = *(float4*)&vv[uu * 4];
        return;
    }
    if (bias) {
        #pragma unroll
        for (int uu = 0; uu < 4; ++uu) {
            float4 b4 = *(const float4*)(bias + nb + uu * 4);
            vv[uu * 4 + 0] += b4.x; vv[uu * 4 + 1] += b4.y;
            vv[uu * 4 + 2] += b4.z; vv[uu * 4 + 3] += b4.w;
        }
    }
    unsigned short ea[16];
    if constexpr (EPI == 2 || EPI == 3 || EPI == 6) {
        *(short8*)&ea[0] = *(const short8*)(exA + idx);
        *(short8*)&ea[8] = *(const short8*)(exA + idx + 8);
    }
    auto store_h = [&](const float* s) {
        unsigned short hb[16];
        #pragma unroll
        for (int e = 0; e < 16; ++e) hb[e] = f2h(s[e]);
        *(short8*)(oh + idx) = *(short8*)hb;
        *(short8*)(oh + idx + 8) = *(short8*)(hb + 8);
    };
    auto store_h2 = [&](const float* s) {
        unsigned short hb[16];
        #pragma unroll
        for (int e = 0; e < 16; ++e) hb[e] = f2h(s[e]);
        *(short8*)(oh2 + idx) = *(short8*)hb;
        *(short8*)(oh2 + idx + 8) = *(short8*)(hb + 8);
    };
    if constexpr (EPI == 0) {
        if (accum) {
            #pragma unroll
            for (int uu = 0; uu < 4; ++uu) {
                float4 o4 = *(const float4*)(C + idx + uu * 4);
                vv[uu * 4 + 0] += o4.x; vv[uu * 4 + 1] += o4.y;
                vv[uu * 4 + 2] += o4.z; vv[uu * 4 + 3] += o4.w;
            }
        }
        #pragma unroll
        for (int uu = 0; uu < 4; ++uu) *(float4*)(C + idx + uu * 4) = *(float4*)&vv[uu * 4];
    } else if constexpr (EPI == 1) {
        float s[16];
        #pragma unroll
        for (int e = 0; e < 16; ++e) s[e] = siluf(vv[e]);
        store_h(s);
    } else if constexpr (EPI == 2) {
        float s[16];
        #pragma unroll
        for (int e = 0; e < 16; ++e) s[e] = h2f(ea[e]) + siluf(vv[e]);
        store_h(s);
    } else if constexpr (EPI == 3) {
        float sc = GS * (2.0f / 512.0f) * lrp[m];
        float s[16];
        #pragma unroll
        for (int e = 0; e < 16; ++e) s[e] = sc * (vv[e] - h2f(ea[e]));
        store_h(s);
    } else if constexpr (EPI == 4) {
        if (accum) {
            #pragma unroll
            for (int uu = 0; uu < 4; ++uu) {
                float4 o4 = *(const float4*)(C + idx + uu * 4);
                vv[uu * 4 + 0] += o4.x; vv[uu * 4 + 1] += o4.y;
                vv[uu * 4 + 2] += o4.z; vv[uu * 4 + 3] += o4.w;
            }
        }
        #pragma unroll
        for (int uu = 0; uu < 4; ++uu) *(float4*)(C + idx + uu * 4) = *(float4*)&vv[uu * 4];
        unsigned short ed[16];
        *(short8*)&ed[0] = *(const short8*)(exD + idx);
        *(short8*)&ed[8] = *(const short8*)(exD + idx + 8);
        float s[16];
        #pragma unroll
        for (int e = 0; e < 16; ++e) s[e] = vv[e] * dsiluf(h2f(ed[e]));
        store_h(s);
    } else if constexpr (EPI == 5) {
        store_h2(vv);
        float s[16];
        #pragma unroll
        for (int e = 0; e < 16; ++e) s[e] = siluf(vv[e]);
        store_h(s);
    } else if constexpr (EPI == 6) {
        store_h2(vv);
        float s[16];
        #pragma unroll
        for (int e = 0; e < 16; ++e) s[e] = h2f(ea[e]) + siluf(vv[e]);
        store_h(s);
    } else if constexpr (EPI == 7) {
        int b2 = m / Nn, t2 = m - b2 * Nn;
        if (t2 >= Mm) {
            float* dst = C + (size_t)(b2 * Ss + (t2 - Mm)) * Nd + nb;
            #pragma unroll
            for (int uu = 0; uu < 4; ++uu) *(float4*)(dst + uu * 4) = *(float4*)&vv[uu * 4];
        }
    } else if constexpr (EPI == 8) {
        store_h(vv);
    }
}

// ---- merged split-K reduce over 4 segments --------------------------------
struct Red4 { float* o[4]; };
__global__ void k_reduce4(const float* __restrict__ part, Red4 r, float alpha) {
    int seg = blockIdx.x >> 10;
    int i = (blockIdx.x & 1023) * 256 + threadIdx.x;
    const float* p = part + (size_t)seg * 11 * WEL;
    float s = 0.f;
    #pragma unroll
    for (int z = 0; z < 11; ++z) s += p[(size_t)z * WEL + i];
    r.o[seg][i] = alpha * s;
}

// ---- merged column sums (bias grads), 4 segments --------------------------
struct CS4 { const unsigned short* g[4]; };
__global__ void k_colsum4(CS4 cs, float* __restrict__ part) {
    int col = blockIdx.x * 256 + threadIdx.x;
    int chunk = blockIdx.y, seg = blockIdx.z;
    const unsigned short* g = cs.g[seg];
    int r0 = chunk * (Rr / 64);
    float s = 0.f;
    for (int r = r0; r < r0 + Rr / 64; ++r) s += h2f(g[(size_t)r * Dd + col]);
    part[((size_t)seg * 64 + chunk) * Dd + col] = s;
}
__global__ void k_colsum_red4(const float* __restrict__ part, Red4 r, float alpha) {
    int col = blockIdx.x * 256 + threadIdx.x;
    int seg = blockIdx.y;
    float s = 0.f;
    #pragma unroll
    for (int c = 0; c < 64; ++c) s += part[((size_t)seg * 64 + c) * Dd + col];
    r.o[seg][col] = alpha * s;
}

// ---- causal depthwise conv K=4 + SiLU (+L2n for q,k); fp16 in/out ---------
__global__ __launch_bounds__(256) void k_conv3(
        const unsigned short* __restrict__ yq, const unsigned short* __restrict__ yk,
        const unsigned short* __restrict__ yv,
        const float* __restrict__ cq, const float* __restrict__ ck, const float* __restrict__ cv,
        unsigned short* oq, unsigned short* ok, unsigned short* ov) {
    int which = blockIdx.y;
    const unsigned short* y = which == 0 ? yq : which == 1 ? yk : yv;
    const float* cw = which == 0 ? cq : which == 1 ? ck : cv;
    unsigned short* oh = which == 0 ? oq : which == 1 ? ok : ov;
    bool norm = which < 2;
    int r = blockIdx.x;
    int b = r / Nn, t = r - b * Nn;
    const size_t rowbase = (size_t)r * Dd;
    float s[2];
    #pragma unroll
    for (int u = 0; u < 2; ++u) {
        int d = threadIdx.x + u * 256;
        float acc = 0.f;
        #pragma unroll
        for (int k = 0; k < 4; ++k) {
            int tt = t - 3 + k;
            if (tt >= 0) acc += h2f(y[(size_t)(b * Nn + tt) * Dd + d]) * cw[d * 4 + k];
        }
        s[u] = siluf(acc);
    }
    float denom = 1.0f;
    if (norm) {
        __shared__ float wr[4];
        float v2 = s[0] * s[0] + s[1] * s[1];
        #pragma unroll
        for (int off = 32; off; off >>= 1) v2 += __shfl_xor(v2, off, 64);
        if ((threadIdx.x & 63) == 0) wr[threadIdx.x >> 6] = v2;
        __syncthreads();
        denom = fmaxf(sqrtf(wr[0] + wr[1] + wr[2] + wr[3]), 1e-12f);
    }
    oh[rowbase + threadIdx.x]       = f2h(s[0] / denom);
    oh[rowbase + threadIdx.x + 256] = f2h(s[1] / denom);
}

// ---- weight update + transpose to fp16 [c][r] via LDS ---------------------
struct UpdW4 { const float* p[4]; const float* mo[4]; const float* g[4]; unsigned short* th[4]; };
__global__ __launch_bounds__(256) void k_updW(UpdW4 u, const float* __restrict__ scal) {
    __shared__ float T[64][65];
    int seg = blockIdx.z;
    int r0 = blockIdx.y * 64, c0 = blockIdx.x * 64;
    float a = 1.0f - scal[0], et = scal[2], th = scal[1];
    int tr = threadIdx.x >> 2, tc = (threadIdx.x & 3) * 16;
    size_t base = (size_t)(r0 + tr) * 512 + c0 + tc;
    #pragma unroll
    for (int q = 0; q < 4; ++q) {
        float4 p4 = *(const float4*)(u.p[seg] + base + q * 4);
        float4 m4 = *(const float4*)(u.mo[seg] + base + q * 4);
        float4 g4 = *(const float4*)(u.g[seg] + base + q * 4);
        T[tr][tc + q * 4 + 0] = p4.x * a + et * m4.x - th * g4.x;
        T[tr][tc + q * 4 + 1] = p4.y * a + et * m4.y - th * g4.y;
        T[tr][tc + q * 4 + 2] = p4.z * a + et * m4.z - th * g4.z;
        T[tr][tc + q * 4 + 3] = p4.w * a + et * m4.w - th * g4.w;
    }
    __syncthreads();
    int c = threadIdx.x >> 2, rb = (threadIdx.x & 3) * 16;
    unsigned short o16[16];
    #pragma unroll
    for (int e = 0; e < 16; ++e) o16[e] = f2h(T[rb + e][c]);
    unsigned short* tp = u.th[seg] + (size_t)(c0 + c) * 512 + r0 + rb;
    *(short8*)tp = *(short8*)o16; *(short8*)(tp + 8) = *(short8*)(o16 + 8);
}
struct UpdB4 { const float* p[4]; const float* mo[4]; const float* g[4]; float* o[4]; };
__global__ void k_updB(UpdB4 u, const float* __restrict__ scal) {
    int seg = blockIdx.x >> 1;
    int i = (blockIdx.x & 1) * 256 + threadIdx.x;
    u.o[seg][i] = u.p[seg][i] * (1.0f - scal[0]) + scal[2] * u.mo[seg][i] - scal[1] * u.g[seg][i];
}

// ---- fused MFMA flash SWA (fp16 in/out) -----------------------------------
__global__ __launch_bounds__(256) void k_swa(const unsigned short* __restrict__ qs,
                                             const unsigned short* __restrict__ ks,
                                             const unsigned short* __restrict__ vs,
                                             unsigned short* __restrict__ out) {
    __shared__ unsigned short KH[2048], VH[2048];
    __shared__ unsigned short PH[4][512];
    const int tid = threadIdx.x;
    const int w = tid >> 6, lane = tid & 63;
    const int lq = lane >> 4, l16 = lane & 15;
    const int q0 = blockIdx.x * 64;
    const int bh = blockIdx.y;
    const int h = bh & 7, b = bh >> 3;
    const size_t srow = (size_t)(b * Nn) * Dd + h * HD;
    const int iq = q0 + w * 16 + l16;

    half8 qh[2];
    {
        const unsigned short* qr = qs + srow + (size_t)iq * Dd;
        qh[0] = *(const half8*)(qr + lq * 8);
        qh[1] = *(const half8*)(qr + 32 + lq * 8);
    }

    f32x4 o[4];
    #pragma unroll
    for (int nf = 0; nf < 4; ++nf)
        #pragma unroll
        for (int v = 0; v < 4; ++v) o[nf][v] = 0.f;
    float mrun[4] = { -1e30f, -1e30f, -1e30f, -1e30f };
    float lrun[4] = { 0.f, 0.f, 0.f, 0.f };
    const int iw = q0 + w * 16 + lq * 4;

    int jlo = q0 - (WINw - 1); if (jlo < 0) jlo = 0;
    jlo &= ~31;
    for (int jt = jlo; jt < q0 + 64; jt += 32) {
        __syncthreads();
        {
            int nr = tid >> 3, ds8 = (tid & 7) * 8;
            short8 kv = *(const short8*)(ks + srow + (size_t)(jt + nr) * Dd + ds8);
            int f = nr >> 4, rr = nr & 15, kf = ds8 >> 5, q = (ds8 >> 3) & 3;
            int u = swz(((f * 2 + kf) * 4 + q) * 16 + rr);
            *(short8*)(KH + u * 8) = kv;
        }
        {
            int d = tid & 63, kg = tid >> 6;
            unsigned short hh[8];
            #pragma unroll
            for (int e = 0; e < 8; ++e)
                hh[e] = vs[srow + (size_t)(jt + kg * 8 + e) * Dd + d];
            int f = d >> 4, rr = d & 15;
            int u = swz((f * 4 + kg) * 16 + rr);
            *(short8*)(VH + u * 8) = *(short8*)hh;
        }
        __syncthreads();

        f32x4 s[2];
        #pragma unroll
        for (int nf = 0; nf < 2; ++nf) {
            #pragma unroll
            for (int v = 0; v < 4; ++v) s[nf][v] = 0.f;
            #pragma unroll
            for (int kf = 0; kf < 2; ++kf) {
                int u = swz(((nf * 2 + kf) * 4 + lq) * 16 + l16);
                half8 kb = *(const half8*)(KH + u * 8);
                s[nf] = __builtin_amdgcn_mfma_f32_16x16x32_f16(qh[kf], kb, s[nf], 0, 0, 0);
            }
        }
        float mt[4];
        #pragma unroll
        for (int v = 0; v < 4; ++v) {
            int i = iw + v;
            int j0c = jt + l16, j1c = jt + 16 + l16;
            s[0][v] = ((j0c <= i) && (i - j0c < WINw)) ? s[0][v] * 0.125f : -1e30f;
            s[1][v] = ((j1c <= i) && (i - j1c < WINw)) ? s[1][v] * 0.125f : -1e30f;
            mt[v] = fmaxf(s[0][v], s[1][v]);
        }
        #pragma unroll
        for (int msk = 1; msk < 16; msk <<= 1)
            #pragma unroll
            for (int v = 0; v < 4; ++v) mt[v] = fmaxf(mt[v], __shfl_xor(mt[v], msk, 64));
        float rs[4];
        #pragma unroll
        for (int v = 0; v < 4; ++v) {
            float mnew = fmaxf(mrun[v], mt[v]);
            float corr = __expf(mrun[v] - mnew);
            mrun[v] = mnew;
            float p0 = (s[0][v] > -1e29f) ? __expf(s[0][v] - mnew) : 0.f;
            float p1 = (s[1][v] > -1e29f) ? __expf(s[1][v] - mnew) : 0.f;
            s[0][v] = p0; s[1][v] = p1;
            rs[v] = p0 + p1;
            lrun[v] *= corr;
            #pragma unroll
            for (int nf = 0; nf < 4; ++nf) o[nf][v] *= corr;
        }
        #pragma unroll
        for (int msk = 1; msk < 16; msk <<= 1)
            #pragma unroll
            for (int v = 0; v < 4; ++v) rs[v] += __shfl_xor(rs[v], msk, 64);
        #pragma unroll
        for (int v = 0; v < 4; ++v) lrun[v] += rs[v];

        #pragma unroll
        for (int nf = 0; nf < 2; ++nf)
            #pragma unroll
            for (int v = 0; v < 4; ++v) {
                int row = lq * 4 + v;
                int cu = (nf * 2 + (l16 >> 3)) ^ (row >> 2);
                PH[w][row * 32 + cu * 8 + (l16 & 7)] = f2h(s[nf][v]);
            }
        __syncthreads();
        int pa = l16 * 32 + (lq ^ (l16 >> 2)) * 8;
        half8 pah = *(const half8*)(&PH[w][pa]);
        #pragma unroll
        for (int nf = 0; nf < 4; ++nf) {
            int u = swz((nf * 4 + lq) * 16 + l16);
            half8 vth = *(const half8*)(VH + u * 8);
            o[nf] = __builtin_amdgcn_mfma_f32_16x16x32_f16(pah, vth, o[nf], 0, 0, 0);
        }
    }
    float invl[4];
    #pragma unroll
    for (int v = 0; v < 4; ++v) invl[v] = 1.0f / lrun[v];
    #pragma unroll
    for (int nf = 0; nf < 4; ++nf)
        #pragma unroll
        for (int v = 0; v < 4; ++v)
            out[srow + (size_t)(iw + v) * Dd + nf * 16 + l16] = f2h(o[nf][v] * invl[v]);
}

} // namespace

extern "C" void kernel_launch(void* const* d_in, const int* in_sizes, int n_in,
                              void* d_out, int out_size, void* d_ws, size_t ws_size,
                              hipStream_t stream) {
    const float* x       = (const float*)d_in[0];
    const float* meta    = (const float*)d_in[1];
    const float* mWin    = (const float*)d_in[2];
    const float* mbin    = (const float*)d_in[3];
    const float* mWh     = (const float*)d_in[4];
    const float* mbh     = (const float*)d_in[5];
    const float* mWout   = (const float*)d_in[6];
    const float* mbout   = (const float*)d_in[7];
    const float* momWin  = (const float*)d_in[8];
    const float* mombin  = (const float*)d_in[9];
    const float* momWh   = (const float*)d_in[10];
    const float* mombh   = (const float*)d_in[11];
    const float* momWout = (const float*)d_in[12];
    const float* mombout = (const float*)d_in[13];
    const float* q_w = (const float*)d_in[14]; const float* q_b = (const float*)d_in[15]; const float* q_c = (const float*)d_in[16];
    const float* k_w = (const float*)d_in[17]; const float* k_b = (const float*)d_in[18]; const float* k_c = (const float*)d_in[19];
    const float* v_w = (const float*)d_in[20]; const float* v_b = (const float*)d_in[21]; const float* v_c = (const float*)d_in[22];
    const float* lr_w = (const float*)d_in[23]; const float* lr_b = (const float*)d_in[24];
    const float* fg_w = (const float*)d_in[25]; const float* fg_b = (const float*)d_in[26];
    const float* mo_w = (const float*)d_in[27]; const float* mo_b = (const float*)d_in[28];
    const float* swa_wq = (const float*)d_in[29]; const float* swa_wk = (const float*)d_in[30];
    const float* swa_wv = (const float*)d_in[31]; const float* swa_wo = (const float*)d_in[32];
    const float* swa_bq = (const float*)d_in[33]; const float* swa_bk = (const float*)d_in[34];
    const float* swa_bv = (const float*)d_in[35]; const float* swa_bo = (const float*)d_in[36];
    (void)in_sizes; (void)n_in; (void)out_size; (void)ws_size;

    char* wsb = (char*)d_ws;
    size_t off = 0;
    auto allocB = [&](size_t bytes) { void* p = wsb + off; off = (off + bytes + 255) & ~(size_t)255; return p; };
    auto allocU = [&](size_t elems) { return (unsigned short*)allocB(elems * 2); };
    auto allocF = [&](size_t elems) { return (float*)allocB(elems * 4); };

    unsigned short *xm_h = allocU(NBD);       // -> da1 after Phase A
    unsigned short *qb_h = allocU(NBD);
    unsigned short *kb_h = allocU(NBD);       // -> swa-out after GRADW4
    unsigned short *vb_h = allocU(NBD);       // -> dz0 after dpred
    unsigned short *h0_h = allocU(NBD);
    unsigned short *h1_h = allocU(NBD);
    unsigned short *h2_h = allocU(NBD);
    unsigned short *g1_h = allocU(NBD);
    unsigned short *z0p  = allocU(NBD);       // pre-acts; -> swa q after Phase C
    unsigned short *a0p  = allocU(NBD);       // -> swa k
    unsigned short *a1p  = allocU(NBD);       // -> swa v
    unsigned short *da0  = allocU(NBD);
    float *f3 = allocF(NBD);                  // dh-chain fp32 accumulator
    float *parts = allocF((size_t)44 * WEL);
    unsigned short *wt_h[11], *wn_h[11];
    for (int i = 0; i < 11; ++i) { wt_h[i] = allocU(WEL); wn_h[i] = nullptr; }
    for (int i = 8; i < 11; ++i) wn_h[i] = allocU(WEL);
    unsigned short *nWinT_h = allocU(WEL);
    unsigned short *nWh0T_h = allocU(WEL);
    unsigned short *nWh1T_h = allocU(WEL);
    unsigned short *nWoutT_h = allocU(WEL);
    float *gWin = allocF(WEL), *gWh0 = allocF(WEL), *gWh1 = allocF(WEL), *gWout = allocF(WEL);
    float *gbin = allocF(512), *gbh0 = allocF(512), *gbh1 = allocF(512), *gbout = allocF(512);
    float *nbin = allocF(512), *nbh0 = allocF(512), *nbh1 = allocF(512), *nbout = allocF(512);
    float *lr_t = allocF(Rr), *fg_t = allocF(Rr), *mo_t = allocF(Rr);
    float *scal = allocF(8);
    float *cpart = allocF(4 * 64 * 512);
    unsigned short *da1 = xm_h;
    unsigned short *dz0 = vb_h;
    unsigned short *soh = kb_h;

    TriSet none{}; Grad4 g0{};
    const dim3 GG(66, 8);
    const float GALPHA = 1.0f / (NCc * GS);

    // ---- weight conversion ----
    WC wc{};
    const float* wlist[11] = { q_w, k_w, v_w, swa_wq, swa_wk, swa_wv, swa_wo,
                               mWin, mWh, mWh + WEL, mWout };
    for (int i = 0; i < 11; ++i) { wc.w[i] = wlist[i]; wc.th[i] = wt_h[i]; wc.nh[i] = wn_h[i]; }
    k_wconv<<<dim3(8, 8, 11), 256, 0, stream>>>(wc);

    // ---- Phase A ----
    k_build_xm<<<(Rr * 128 + 255) / 256, 256, 0, stream>>>(x, meta, xm_h);
    k_gates<<<Rr / 4, 256, 0, stream>>>(xm_h, lr_w, lr_b, fg_w, fg_b, mo_w, mo_b, lr_t, fg_t, mo_t);
    k_gate_means<<<1, 256, 0, stream>>>(lr_t, fg_t, mo_t, scal);

    TriSet qkvA{{ { wt_h[0], q_b, h0_h }, { wt_h[1], k_b, h1_h }, { wt_h[2], v_b, h2_h } }};
    k_mm<0, 0, false, 8, true, false><<<dim3(66, 8, 3), 256, 0, stream>>>(
        xm_h, nullptr, nullptr, nullptr, nullptr, nullptr, nullptr, nullptr, nullptr,
        qkvA, g0, Rr, Dd, Dd, 0);
    k_conv3<<<dim3(Rr, 3), 256, 0, stream>>>(h0_h, h1_h, h2_h, q_c, k_c, v_c, qb_h, kb_h, vb_h);

    // ---- Phase B: memory-MLP forward (pre-acts fp16) ----
    k_mm<0, 0, false, 5, false, false><<<GG, 256, 0, stream>>>(
        kb_h, wt_h[7], nullptr, mbin, nullptr, nullptr, nullptr, h0_h, z0p, none, g0, Rr, Dd, Dd, 0);
    k_mm<0, 0, false, 6, false, false><<<GG, 256, 0, stream>>>(
        h0_h, wt_h[8], nullptr, mbh, h0_h, nullptr, nullptr, h1_h, a0p, none, g0, Rr, Dd, Dd, 0);
    k_mm<0, 0, false, 6, false, false><<<GG, 256, 0, stream>>>(
        h1_h, wt_h[9], nullptr, mbh + 512, h1_h, nullptr, nullptr, h2_h, a1p, none, g0, Rr, Dd, Dd, 0);
    k_mm<0, 0, false, 3, false, false><<<GG, 256, 0, stream>>>(
        h2_h, wt_h[10], nullptr, mbout, vb_h, nullptr, lr_t, g1_h, nullptr, none, g0, Rr, Dd, Dd, 0);

    // ---- Phase C: dh chain (fp32 accum in f3), then merged GRADW ----
    k_mm<0, 0, false, 4, false, false><<<GG, 256, 0, stream>>>(
        g1_h, wn_h[10], f3, nullptr, nullptr, a1p, nullptr, da1, nullptr, none, g0, Rr, Dd, Dd, 0);
    k_mm<0, 0, false, 4, false, false><<<GG, 256, 0, stream>>>(
        da1, wn_h[9], f3, nullptr, nullptr, a0p, nullptr, da0, nullptr, none, g0, Rr, Dd, Dd, 1);
    k_mm<0, 0, false, 4, false, false><<<GG, 256, 0, stream>>>(
        da0, wn_h[8], f3, nullptr, nullptr, z0p, nullptr, dz0, nullptr, none, g0, Rr, Dd, Dd, 1);
    Grad4 g4{{ h2_h, h1_h, h0_h, kb_h }, { g1_h, da1, da0, dz0 }};
    k_mm<1, 1, true, 0, false, true><<<dim3(8, 8, 44), 256, 0, stream>>>(
        nullptr, nullptr, parts, nullptr, nullptr, nullptr, nullptr, nullptr, nullptr,
        none, g4, Dd, Dd, Rr, 0);
    Red4 rw{{ gWout, gWh1, gWh0, gWin }};
    k_reduce4<<<4096, 256, 0, stream>>>(parts, rw, GALPHA);
    CS4 cs{{ g1_h, da1, da0, dz0 }};
    k_colsum4<<<dim3(2, 64, 4), 256, 0, stream>>>(cs, cpart);
    Red4 rb{{ gbout, gbh1, gbh0, gbin }};
    k_colsum_red4<<<dim3(2, 4), 256, 0, stream>>>(cpart, rb, GALPHA);

    // ---- Phase D: updates ----
    UpdW4 uw{ { mWin, mWh, mWh + WEL, mWout },
              { momWin, momWh, momWh + WEL, momWout },
              { gWin, gWh0, gWh1, gWout },
              { nWinT_h, nWh0T_h, nWh1T_h, nWoutT_h } };
    k_updW<<<dim3(8, 8, 4), 256, 0, stream>>>(uw, scal);
    UpdB4 ub{ { mbin, mbh, mbh + 512, mbout },
              { mombin, mombh, mombh + 512, mombout },
              { gbin, gbh0, gbh1, gbout },
              { nbin, nbh0, nbh1, nbout } };
    k_updB<<<8, 256, 0, stream>>>(ub, scal);

    // ---- Phase E: retrieval MLP on q ----
    k_mm<0, 0, false, 1, false, false><<<GG, 256, 0, stream>>>(
        qb_h, nWinT_h, nullptr, nbin, nullptr, nullptr, nullptr, g1_h, nullptr, none, g0, Rr, Dd, Dd, 0);
    k_mm<0, 0, false, 2, false, false><<<GG, 256, 0, stream>>>(
        g1_h, nWh0T_h, nullptr, nbh0, g1_h, nullptr, nullptr, h0_h, nullptr, none, g0, Rr, Dd, Dd, 0);
    k_mm<0, 0, false, 2, false, false><<<GG, 256, 0, stream>>>(
        h0_h, nWh1T_h, nullptr, nbh1, h0_h, nullptr, nullptr, h1_h, nullptr, none, g0, Rr, Dd, Dd, 0);
    k_mm<0, 0, false, 1, false, false><<<GG, 256, 0, stream>>>(
        h1_h, nWoutT_h, nullptr, nbout, nullptr, nullptr, nullptr, h2_h, nullptr, none, g0, Rr, Dd, Dd, 0);

    // ---- Phase F: SWA qkv (fp16), MFMA flash SWA, out-proj+slice ----
    TriSet qkvF{{ { wt_h[3], swa_bq, z0p }, { wt_h[4], swa_bk, a0p }, { wt_h[5], swa_bv, a1p } }};
    k_mm<0, 0, false, 8, true, false><<<dim3(66, 8, 3), 256, 0, stream>>>(
        h2_h, nullptr, nullptr, nullptr, nullptr, nullptr, nullptr, nullptr, nullptr,
        qkvF, g0, Rr, Dd, Dd, 0);
    k_swa<<<dim3(Nn / 64, Bb * NHh), 256, 0, stream>>>(z0p, a0p, a1p, soh);
    k_mm<0, 0, false, 7, false, false><<<GG, 256, 0, stream>>>(
        soh, wt_h[6], (float*)d_out, swa_bo, nullptr, nullptr, nullptr, nullptr, nullptr,
        none, g0, Rr, Dd, Dd, 0);
}